// Round 16
// baseline (21.530 us; speedup 1.0000x reference)
//
#include <hip/hip_runtime.h>

// MakeCutouts: 32 random crops (sz in [224,511]) of a [2,3,512,512] fp32
// image, each adaptive-avg-pooled (PyTorch semantics) to 224x224.
// Output: [32*2, 3, 224, 224] fp32.
//
// R16 = R13 (best, 16.6us: R4 body + balanced XCD row-chunk mapping + nt
// stores, unpadded LDS — R15's pad was null) + bf16 pair-plane packed INPUT.
// Rationale: R11 probe showed body ~10us at ~80% combined HBM BW with
// ~13MB/iter HBM re-fetch (write stream evicts input from 4MiB L2s) and
// ~160MB of L2 reads. Packing 6 fp32 planes into 3 uint32 bf16-pair planes
// (3.15MB) halves read bytes at every level and L2-fits next to the write
// stream. R8 tested this pre-mapping and was null — but the 11us cold-read
// constant masked body changes then. absmax ~1.6e-2 << 5.16e-2 threshold.

constexpr int CUT   = 224;
constexpr int BC    = 6;          // B*C = 2*3
constexpr int HH    = 512;
constexpr int WW    = 512;
constexpr int PIX   = CUT * CUT;  // 50176
constexpr int PLANE = HH * WW;
constexpr int CHUNK = CUT / 8;    // 28 rows per XCD per cutout

__device__ __forceinline__ uint32_t bf16_rtne(float f) {
    const uint32_t u = __float_as_uint(f);
    return (u + 0x7FFFu + ((u >> 16) & 1u)) >> 16;
}

// Pass 0: w[pr][y][x] = bf16(in[2pr][y][x]) | bf16(in[2pr+1][y][x]) << 16.
__global__ __launch_bounds__(256) void pack_bf16_kernel(
    const float* __restrict__ in,   // [6][512][512]
    uint32_t*    __restrict__ w)    // [3][512][512]
{
    const int gid = blockIdx.x * 256 + threadIdx.x;   // 0..196607
    const int pr  = gid / (PLANE / 4);                // 0..2
    const int e   = (gid - pr * (PLANE / 4)) * 4;     // pixel index, x4

    const float4 lo = *(const float4*)(in + (2 * pr    ) * PLANE + e);
    const float4 hi = *(const float4*)(in + (2 * pr + 1) * PLANE + e);
    uint4 o;
    o.x = bf16_rtne(lo.x) | (bf16_rtne(hi.x) << 16);
    o.y = bf16_rtne(lo.y) | (bf16_rtne(hi.y) << 16);
    o.z = bf16_rtne(lo.z) | (bf16_rtne(hi.z) << 16);
    o.w = bf16_rtne(lo.w) | (bf16_rtne(hi.w) << 16);
    *(uint4*)(w + pr * PLANE + e) = o;
}

__global__ __launch_bounds__(256) void cutout_kernel(
    const uint32_t* __restrict__ w,   // [3][512][512] packed bf16 pairs
    const int* __restrict__ sizes,    // [32]
    const int* __restrict__ offx,     // [32]
    const int* __restrict__ offy,     // [32]
    float*     __restrict__ out)      // [32, 6, 224, 224] flat
{
    __shared__ float2 vsum[3][WW];    // [plane-pair][crop col] = 12 KB

    // Balanced XCD-affine decode: bid%8 = XCD (round-robin dispatch),
    // XCD x gets rows 28x..28x+27 of every cutout, r-major within a cutout.
    const int bid = blockIdx.x;
    const int xcd = bid & 7;
    const int idx = bid >> 3;          // 0..895 = n*28 + r
    const int n   = idx / CHUNK;       // cutout
    const int r0  = idx - n * CHUNK;   // 0..27
    const int i   = xcd * CHUNK + r0;  // output row

    const int t = threadIdx.x;

    const int sz = sizes[n];          // uniform -> scalar
    const int oy = offy[n];
    const int ox = offx[n];

    const int sy = (i * sz) / CUT;                        // uniform
    const int dy = ((i + 1) * sz + CUT - 1) / CUT - sy;   // 1..4, uniform

    const uint32_t* __restrict__ base = w + (oy + sy) * WW + ox;
    const bool c0 = t < sz;           // sz >= 224; only lanes 224..255 can fail
    const bool c1 = t + 256 < sz;

    // Phase 1: vertical sums over dy rows, cols t and t+256 (crop-relative).
    float a0=0.f,a1=0.f,a2=0.f,a3=0.f,a4=0.f,a5=0.f;  // col t
    float b0=0.f,b1=0.f,b2=0.f,b3=0.f,b4=0.f,b5=0.f;  // col t+256
    for (int r = 0; r < dy; ++r) {    // uniform trip count
        const uint32_t* __restrict__ rp = base + r * WW;
        if (c0) {
            const uint32_t v0 = rp[0*PLANE + t];
            const uint32_t v1 = rp[1*PLANE + t];
            const uint32_t v2 = rp[2*PLANE + t];
            a0 += __uint_as_float(v0 << 16); a1 += __uint_as_float(v0 & 0xFFFF0000u);
            a2 += __uint_as_float(v1 << 16); a3 += __uint_as_float(v1 & 0xFFFF0000u);
            a4 += __uint_as_float(v2 << 16); a5 += __uint_as_float(v2 & 0xFFFF0000u);
        }
        if (c1) {
            const int u = t + 256;
            const uint32_t v0 = rp[0*PLANE + u];
            const uint32_t v1 = rp[1*PLANE + u];
            const uint32_t v2 = rp[2*PLANE + u];
            b0 += __uint_as_float(v0 << 16); b1 += __uint_as_float(v0 & 0xFFFF0000u);
            b2 += __uint_as_float(v1 << 16); b3 += __uint_as_float(v1 & 0xFFFF0000u);
            b4 += __uint_as_float(v2 << 16); b5 += __uint_as_float(v2 & 0xFFFF0000u);
        }
    }
    if (c0) {
        vsum[0][t] = make_float2(a0, a1);
        vsum[1][t] = make_float2(a2, a3);
        vsum[2][t] = make_float2(a4, a5);
    }
    if (c1) {
        const int u = t + 256;
        vsum[0][u] = make_float2(b0, b1);
        vsum[1][u] = make_float2(b2, b3);
        vsum[2][u] = make_float2(b4, b5);
    }
    __syncthreads();

    // Phase 2: horizontal pooling from LDS, 4 predicated taps (dx in 1..4).
    if (t < CUT) {
        const int sx = (t * sz) / CUT;                        // crop-relative
        const int dx = ((t + 1) * sz + CUT - 1) / CUT - sx;   // 1..4
        const int x1 = sx + (dx > 1 ? 1 : 0);                 // clamped taps
        const int x2 = x1 + (dx > 2 ? 1 : 0);
        const int x3 = x2 + (dx > 3 ? 1 : 0);
        const float w1 = dx > 1 ? 1.f : 0.f;
        const float w2 = dx > 2 ? 1.f : 0.f;
        const float w3 = dx > 3 ? 1.f : 0.f;
        const float rr = __builtin_amdgcn_rcpf((float)(dy * dx));

        float* o = out + (size_t)n * BC * PIX + i * CUT + t;
        #pragma unroll
        for (int pr = 0; pr < 3; ++pr) {
            const float2 v0 = vsum[pr][sx];
            const float2 v1 = vsum[pr][x1];
            const float2 v2 = vsum[pr][x2];
            const float2 v3 = vsum[pr][x3];
            const float se = v0.x + w1 * v1.x + w2 * v2.x + w3 * v3.x;
            const float so = v0.y + w1 * v1.y + w2 * v2.y + w3 * v3.y;
            __builtin_nontemporal_store(se * rr, o + (2 * pr    ) * PIX);
            __builtin_nontemporal_store(so * rr, o + (2 * pr + 1) * PIX);
        }
    }
}

extern "C" void kernel_launch(void* const* d_in, const int* in_sizes, int n_in,
                              void* d_out, int out_size, void* d_ws, size_t ws_size,
                              hipStream_t stream) {
    const float* in    = (const float*)d_in[0];
    const int*   sizes = (const int*)d_in[1];
    const int*   offx  = (const int*)d_in[2];
    const int*   offy  = (const int*)d_in[3];
    float*       out   = (float*)d_out;
    uint32_t*    w     = (uint32_t*)d_ws;   // 3*512*512*4 B = 3.15 MB

    pack_bf16_kernel<<<dim3(3 * PLANE / 4 / 256), dim3(256), 0, stream>>>(in, w);
    cutout_kernel<<<dim3(CUT * 32), dim3(256), 0, stream>>>(w, sizes, offx, offy, out);
}

// Round 17
// 16.410 us; speedup vs baseline: 1.3119x; 1.3119x over previous
//
#include <hip/hip_runtime.h>

// MakeCutouts: 32 random crops (sz in [224,511]) of a [2,3,512,512] fp32
// image, each adaptive-avg-pooled (PyTorch semantics) to 224x224.
// Output: [32*2, 3, 224, 224] fp32.
//
// FINAL = R13 (measured best, 16.6us), reverting R16's bf16 pack (+4.9us),
// R15's LDS pad (null), R14's plain stores (+3.0us).
// Structure: R4 cooperative body (block = one output row of one cutout;
// coalesced fp32 loads, uniform dy-loop, stride-8 LDS, nt stores) +
// R12's balanced XCD-affine row-chunk mapping (bid%8=XCD, XCD x owns rows
// [28x,28x+28) of EVERY cutout -> perfect balance + L2-hit dy-overlap;
// fixed the 11us cold-read flood found by R11's REPEAT probe).
// nt stores protect the L2 input working set from the 38MB write stream
// (A/B: 16.6 vs 19.6 plain). Steady body ~10us at 5.1 TB/s combined HBM
// (~80% achievable), write floor 5.8us, launch ~2us -> near envelope.

constexpr int CUT   = 224;
constexpr int BC    = 6;          // B*C = 2*3
constexpr int HH    = 512;
constexpr int WW    = 512;
constexpr int PIX   = CUT * CUT;  // 50176
constexpr int PLANE = HH * WW;
constexpr int CHUNK = CUT / 8;    // 28 rows per XCD per cutout

__global__ __launch_bounds__(256) void cutout_kernel(
    const float* __restrict__ in,     // [6, 512, 512] planes
    const int*   __restrict__ sizes,  // [32]
    const int*   __restrict__ offx,   // [32]
    const int*   __restrict__ offy,   // [32]
    float*       __restrict__ out)    // [32, 6, 224, 224] flat
{
    __shared__ float2 vsum[3][WW];    // [plane-pair][crop col] = 12 KB

    // Balanced XCD-affine decode: bid%8 = XCD (round-robin dispatch),
    // XCD x gets rows 28x..28x+27 of every cutout, r-major within a cutout.
    const int bid = blockIdx.x;
    const int xcd = bid & 7;
    const int idx = bid >> 3;          // 0..895 = n*28 + r
    const int n   = idx / CHUNK;       // cutout
    const int r0  = idx - n * CHUNK;   // 0..27
    const int i   = xcd * CHUNK + r0;  // output row

    const int t = threadIdx.x;

    const int sz = sizes[n];          // uniform -> scalar
    const int oy = offy[n];
    const int ox = offx[n];

    const int sy = (i * sz) / CUT;                        // uniform
    const int dy = ((i + 1) * sz + CUT - 1) / CUT - sy;   // 1..4, uniform

    const float* __restrict__ base = in + (oy + sy) * WW + ox;
    const bool c0 = t < sz;           // sz >= 224; only lanes 224..255 can fail
    const bool c1 = t + 256 < sz;

    // Phase 1: vertical sums over dy rows, cols t and t+256 (crop-relative).
    float a0=0.f,a1=0.f,a2=0.f,a3=0.f,a4=0.f,a5=0.f;  // col t
    float b0=0.f,b1=0.f,b2=0.f,b3=0.f,b4=0.f,b5=0.f;  // col t+256
    for (int r = 0; r < dy; ++r) {    // uniform trip count
        const float* __restrict__ rp = base + r * WW;
        if (c0) {
            a0 += rp[0*PLANE + t]; a1 += rp[1*PLANE + t]; a2 += rp[2*PLANE + t];
            a3 += rp[3*PLANE + t]; a4 += rp[4*PLANE + t]; a5 += rp[5*PLANE + t];
        }
        if (c1) {
            const int u = t + 256;
            b0 += rp[0*PLANE + u]; b1 += rp[1*PLANE + u]; b2 += rp[2*PLANE + u];
            b3 += rp[3*PLANE + u]; b4 += rp[4*PLANE + u]; b5 += rp[5*PLANE + u];
        }
    }
    if (c0) {
        vsum[0][t] = make_float2(a0, a1);
        vsum[1][t] = make_float2(a2, a3);
        vsum[2][t] = make_float2(a4, a5);
    }
    if (c1) {
        const int u = t + 256;
        vsum[0][u] = make_float2(b0, b1);
        vsum[1][u] = make_float2(b2, b3);
        vsum[2][u] = make_float2(b4, b5);
    }
    __syncthreads();

    // Phase 2: horizontal pooling from LDS, 4 predicated taps (dx in 1..4).
    if (t < CUT) {
        const int sx = (t * sz) / CUT;                        // crop-relative
        const int dx = ((t + 1) * sz + CUT - 1) / CUT - sx;   // 1..4
        const int x1 = sx + (dx > 1 ? 1 : 0);                 // clamped taps
        const int x2 = x1 + (dx > 2 ? 1 : 0);
        const int x3 = x2 + (dx > 3 ? 1 : 0);
        const float w1 = dx > 1 ? 1.f : 0.f;
        const float w2 = dx > 2 ? 1.f : 0.f;
        const float w3 = dx > 3 ? 1.f : 0.f;
        const float rr = __builtin_amdgcn_rcpf((float)(dy * dx));

        float* o = out + (size_t)n * BC * PIX + i * CUT + t;
        #pragma unroll
        for (int pr = 0; pr < 3; ++pr) {
            const float2 v0 = vsum[pr][sx];
            const float2 v1 = vsum[pr][x1];
            const float2 v2 = vsum[pr][x2];
            const float2 v3 = vsum[pr][x3];
            const float se = v0.x + w1 * v1.x + w2 * v2.x + w3 * v3.x;
            const float so = v0.y + w1 * v1.y + w2 * v2.y + w3 * v3.y;
            __builtin_nontemporal_store(se * rr, o + (2 * pr    ) * PIX);
            __builtin_nontemporal_store(so * rr, o + (2 * pr + 1) * PIX);
        }
    }
}

extern "C" void kernel_launch(void* const* d_in, const int* in_sizes, int n_in,
                              void* d_out, int out_size, void* d_ws, size_t ws_size,
                              hipStream_t stream) {
    const float* in    = (const float*)d_in[0];
    const int*   sizes = (const int*)d_in[1];
    const int*   offx  = (const int*)d_in[2];
    const int*   offy  = (const int*)d_in[3];
    float*       out   = (float*)d_out;

    cutout_kernel<<<dim3(CUT * 32), dim3(256), 0, stream>>>(
        in, sizes, offx, offy, out);
}